// Round 12
// baseline (187.765 us; speedup 1.0000x reference)
//
#include <hip/hip_runtime.h>
#include <cstdint>

typedef __attribute__((ext_vector_type(8)))  short bf16x8;   // 8 x bf16 (4 VGPR)
typedef __attribute__((ext_vector_type(16))) float f32x16;   // MFMA 32x32 acc
typedef __attribute__((ext_vector_type(4)))  int   i32x4;

__device__ __forceinline__ unsigned short f2bf(float x) {    // RNE fp32->bf16
  unsigned u = __float_as_uint(x);
  u += 0x7fffu + ((u >> 16) & 1u);
  return (unsigned short)(u >> 16);
}
// packed f32x2 -> bf16x2 in ONE instruction (no builtin on gfx950; inline asm)
__device__ __forceinline__ unsigned pk2bf(float lo, float hi) {
  unsigned r;
  asm("v_cvt_pk_bf16_f32 %0, %1, %2" : "=v"(r) : "v"(lo), "v"(hi));
  return r;
}
__device__ __forceinline__ float silu_f(float v) {
  return v * __builtin_amdgcn_rcpf(1.0f + __expf(-v));
}

// half-exchange without the LDS pipe: lanes 0-31 receive A from lane+32,
// lanes 32-63 receive B from lane-32  (== __shfl_xor(q ? A : B, 32)).
__device__ __forceinline__ float xchg32(float A, float B, int q) {
#if defined(__has_builtin)
#if __has_builtin(__builtin_amdgcn_permlane32_swap)
  auto r = __builtin_amdgcn_permlane32_swap(__float_as_uint(A), __float_as_uint(B),
                                            false, false);
  return __uint_as_float(q ? r[0] : r[1]);
#else
  return __shfl_xor(q ? A : B, 32);
#endif
#else
  return __shfl_xor(q ? A : B, 32);
#endif
}

// ---- pack W/3 into MFMA B-frag order via LDS transpose (coalesced R+W).
// dest layout: [layer][g(64 cols)][t(32-col tile)][kt][lane][8], K0 padded 134->144.
__global__ void pack_kernel(const float* __restrict__ W0, const float* __restrict__ W1,
                            const float* __restrict__ W2,
                            unsigned short* __restrict__ packW) {
  __shared__ float ldsF[16][257];
  const int s = blockIdx.x, tid = threadIdx.x;
  const float* W; int KT, kmax, base, kt;
  if (s < 9)       { W = W0; KT = 9;  kmax = 134; base = 0;      kt = s; }
  else if (s < 25) { W = W1; KT = 16; kmax = 256; base = 36864;  kt = s - 9; }
  else             { W = W2; KT = 16; kmax = 256; base = 102400; kt = s - 25; }
  const int k0 = kt * 16;
#pragma unroll
  for (int i = 0; i < 8; ++i) {                 // 512 thr x 8 = 16 x 256 floats
    const int idx = i * 512 + tid;
    const int kl = idx >> 8, col = idx & 255;
    const int kg = k0 + kl;
    ldsF[kl][col] = (kg < kmax) ? W[kg * 256 + col] * 0.33333334f : 0.0f;
  }
  __syncthreads();
  const int g = tid >> 7, t = (tid >> 6) & 1, lane = tid & 63;
  const int col = g * 64 + t * 32 + (lane & 31);
  const int kb = 8 * (lane >> 5);
  unsigned u0 = pk2bf(ldsF[kb + 0][col], ldsF[kb + 1][col]);
  unsigned u1 = pk2bf(ldsF[kb + 2][col], ldsF[kb + 3][col]);
  unsigned u2 = pk2bf(ldsF[kb + 4][col], ldsF[kb + 5][col]);
  unsigned u3 = pk2bf(ldsF[kb + 6][col], ldsF[kb + 7][col]);
  unsigned short* dst = packW + base + g * (KT * 1024) + t * (KT * 512) + kt * 512 + lane * 8;
  i32x4 v = { (int)u0, (int)u1, (int)u2, (int)u3 };
  *(i32x4*)dst = v;
}

// ======================================================================
// r11: 16 waves (1024 thr) = 4 waves/SIMD (2x occupancy). Wave pair (2T,2T+1)
// owns col-tile T (cols 32T..32T+32); wave half = w&1 owns nodes [128h,128h+128)
// = global subs {2h, 2h+1}. acc[2 subs][2 tiles] = 64 VGPR; B-frags STREAMED
// from packW (L2) per kt, depth-1 prefetch (fits the 128-VGPR cap @4 waves/SIMD).
// Layer flow: kloop(all reads) -> bnd scratch -> barrier -> epilogue(all writes)
// -> barrier. No defer/fixup: cross-half boundaries via 4KB LDS bnd.
// Node map: node = 64S + 32t + 16q + r; C row = (r&3)+8*(r>>2)+4q (verified).
// s~[n] = (h W/3)[n] + bias/3; y[n] = silu(s~[n-1]+s~[n]+s~[n+1]).
// L0 temb-fold: tW once per wave (9 MFMAs, broadcast A); L0 K=16 (1 kt).
// h[256][256] bf16 in 128KB LDS, 16B-slot XOR swizzle (slot ^= row&31).
// ======================================================================

__device__ __forceinline__ f32x16 MF(const bf16x8 a, const bf16x8 b, const f32x16 c) {
  return __builtin_amdgcn_mfma_f32_32x32x16_bf16(a, b, c, 0, 0, 0);
}

// kloop over this wave's 2 local subs x 2 tiles; B streamed (one frag feeds 4 MFMAs)
template <int KT>
__device__ __forceinline__ void kloop2(
    const unsigned short* __restrict__ hbufH,   // hbuf + half*32768 (shorts)
    const unsigned short* __restrict__ pB,      // packW layer base for tile T
    const int lane, const int q, const int c,
    const float init, f32x16 acc[2][2]) {
#pragma unroll
  for (int s = 0; s < 2; ++s)
#pragma unroll
    for (int t = 0; t < 2; ++t)
#pragma unroll
      for (int j = 0; j < 16; ++j) acc[s][t][j] = init;
  bf16x8 bcur = *(const bf16x8*)(pB + lane * 8);
  const unsigned short* rb = hbufH + c * 256;
#pragma unroll
  for (int kt = 0; kt < KT; ++kt) {
    bf16x8 bnext;
    if (kt + 1 < KT) bnext = *(const bf16x8*)(pB + (kt + 1) * 512 + lane * 8);
    const unsigned short* ap = rb + (((2 * kt + q) ^ c) * 8);
    const bf16x8 a00 = *(const bf16x8*)(ap);
    const bf16x8 a01 = *(const bf16x8*)(ap + 8192);
    const bf16x8 a10 = *(const bf16x8*)(ap + 16384);
    const bf16x8 a11 = *(const bf16x8*)(ap + 24576);
    acc[0][0] = MF(a00, bcur, acc[0][0]);
    acc[0][1] = MF(a01, bcur, acc[0][1]);
    acc[1][0] = MF(a10, bcur, acc[1][0]);
    acc[1][1] = MF(a11, bcur, acc[1][1]);
    if (kt + 1 < KT) bcur = bnext;
  }
}

// epilogue for ONE sub (32 values as 16 pairs, shared mid); verified boundary
// pattern: extP used by q0/t0/r0, extN by q1/t1/r15; recvI/X via xchg32.
template <int ELAYER>
__device__ __forceinline__ void epi_sub(
    const f32x16* accS, const int q, const float extP, const float extN,
    const int epiSub, unsigned short* __restrict__ hbuf,
    const int* rowAddr, float& psum) {
  const float recvI0 = xchg32(accS[0][0],  accS[0][15], q);
  const float recvI1 = xchg32(accS[1][0],  accS[1][15], q);
  const float recvX  = xchg32(accS[0][15], accS[1][0],  q);
#pragma unroll
  for (int p = 0; p < 16; ++p) {
    const int t = p >> 3, rp = (p & 7) * 2;
    const float mid = accS[t][rp] + accS[t][rp + 1];
    float prev, next;
    if (rp > 0) prev = accS[t][rp - 1];
    else        prev = q ? (t ? recvI1 : recvI0) : (t ? recvX : extP);
    if (rp < 14) next = accS[t][rp + 2];
    else         next = q ? (t ? extN : recvX) : (t ? recvI1 : recvI0);
    const float y0 = silu_f(prev + mid);
    const float y1 = silu_f(mid + next);
    if constexpr (ELAYER == 2) { psum += y0; psum += y1; }
    else {
      const unsigned u = pk2bf(y0, y1);
      char* bp = (char*)hbuf + (2 * epiSub + t) * 16384;
      *(unsigned short*)(bp + rowAddr[rp])     = (unsigned short)u;
      *(unsigned short*)(bp + rowAddr[rp + 1]) = (unsigned short)(u >> 16);
    }
  }
}

// ---------------- main fused kernel: 1 block = 1 graph, 16 waves ----------
__global__ __launch_bounds__(1024, 1) void poly_kernel(
    const float* __restrict__ x, const float* __restrict__ t,
    const float* __restrict__ tw, const float* __restrict__ tb,
    const unsigned short* __restrict__ packW,
    const float* __restrict__ B0, const float* __restrict__ B1,
    const float* __restrict__ B2, float* __restrict__ out) {
  __shared__ __align__(16) unsigned short hbuf[65536];  // 128 KiB, swizzled
  __shared__ __align__(16) unsigned short tmpl[160];    // h0 template (temb+pads)
  __shared__ float bnd[8][4][32];    // [T][{s0,s127,s128,s255}][c] boundary s~
  __shared__ float pool[2][8][32];   // [half][T][c] L2 partial sums

  const int tid = threadIdx.x;
  const int w = tid >> 6, lane = tid & 63, q = lane >> 5, c = lane & 31;
  const int T = w >> 1, half = w & 1;
  const int col = T * 32 + c;
  const int b = blockIdx.x;

  // ---- fused time MLP: temb = silu(sinemb(t[b]) @ tw + tb) ----
  {
    float* scr = (float*)hbuf;        // f32 scratch (overwritten later)
    if (tid < 128) {
      const float tv = t[b];
      const int i = tid & 63;
      const float f = expf(-0.14619588396823767f * (float)i);  // log(1e4)/63
      const float ang = tv * f;
      scr[tid] = (tid < 64) ? sinf(ang) : cosf(ang);
    }
    __syncthreads();
    if (tid < 512) {
      const int j = tid & 127, p = tid >> 7;   // 4-way k-split over 512 threads
      float a = 0.f;
#pragma unroll 8
      for (int kk = 0; kk < 32; ++kk) a += scr[p * 32 + kk] * tw[(p * 32 + kk) * 128 + j];
      scr[128 + tid] = a;
    }
    __syncthreads();
    if (tid < 128) {
      const float a = tb[tid] + scr[128 + tid] + scr[256 + tid] + scr[384 + tid] + scr[512 + tid];
      tmpl[6 + tid] = f2bf(silu_f(a));
      if (tid < 6)  tmpl[tid] = 0;
      if (tid < 26) tmpl[134 + tid] = 0;   // pad k 134..159 = 0
    }
    __syncthreads();
  }

  // packW slice bases for col-tile T
  const unsigned short* pL0 = packW + (T >> 1) * (9 * 1024) + (T & 1) * (9 * 512);
  const unsigned short* pL1 = packW + 36864 + (T >> 1) * (16 * 1024) + (T & 1) * (16 * 512);
  const unsigned short* pL2 = packW + 102400 + (T >> 1) * (16 * 1024) + (T & 1) * (16 * 512);
  const float b30 = B0[col] * 0.33333334f;
  const float b31 = B1[col] * 0.33333334f;
  const float b32 = B2[col] * 0.33333334f;

  // ---- tW fold: node-invariant L0 part (temb @ W0/3) once per wave ----
  float initL0;
  {
    f32x16 Ct;
#pragma unroll
    for (int j = 0; j < 16; ++j) Ct[j] = 0.f;
#pragma unroll
    for (int kt = 0; kt < 9; ++kt) {
      const bf16x8 bk = *(const bf16x8*)(pL0 + kt * 512 + lane * 8);
      const bf16x8 at = *(const bf16x8*)(tmpl + kt * 16 + q * 8);
      Ct = MF(at, bk, Ct);
    }
    initL0 = Ct[0] + b30;
  }

  // ---- build h0 (features only): slots 0,1 per node = [xy, pe, 0-pad] ----
  if (tid < 512) {
    const int node = tid >> 1, sl = tid & 1;
    i32x4 d = {0, 0, 0, 0};
    if (sl == 0) {
      const float2 xy = ((const float2*)x)[b * 256 + node];
      const float th = 0.024543692605870074f * (float)node;   // 2*pi/256
      d.x = (int)pk2bf(xy.x, xy.y);
      d.y = (int)pk2bf(sinf(th), cosf(th));
      d.z = (int)pk2bf(sinf(2.f * th), cosf(2.f * th));
    }
    const int m = (node & 3) + 8 * ((node >> 2) & 3) + 4 * ((node >> 4) & 1);
    const int R = (node & ~31) | m;            // permuted LDS row
    *(i32x4*)(hbuf + R * 256 + ((sl ^ m) * 8)) = d;
  }

  // per-lane h'-write byte addresses (row within tile; r compile-time)
  int rowAddr[16];
  const int slotW = 4 * T + (c >> 3), offW = (c & 7) * 2;    // k-index = col
#pragma unroll
  for (int r = 0; r < 16; ++r) {
    const int row = (r & 3) + 8 * (r >> 2) + 4 * q;
    rowAddr[r] = row * 512 + ((slotW ^ row) * 16) + offW;
  }
  __syncthreads();   // h0 ready

  const unsigned short* hbufH = hbuf + half * 32768;   // this half's rows
  f32x16 acc[2][2];
  float psum = 0.f;

  // ================= L0 (K=16; temb folded into initL0) =================
  kloop2<1>(hbufH, pL0, lane, q, c, initL0, acc);
  bnd[T][half * 2 + q][c] = q ? acc[1][1][15] : acc[0][0][0];   // s~ boundary pub
  __syncthreads();                               // all h0 reads + bnd visible
  {
    const float extP0 = bnd[T][half ? 1 : 3][c];             // s~[127] | s~[255]
    const float extN1 = bnd[T][half ? 0 : 2][c];             // s~[0]   | s~[128]
    const float extN0 = xchg32(0.f, acc[1][0][0], q);        // q1 <- first of sub1
    const float extP1 = xchg32(acc[0][1][15], 0.f, q);       // q0 <- last of sub0
    epi_sub<0>(acc[0], q, extP0, extN0, 2 * half + 0, hbuf, rowAddr, psum);
    epi_sub<0>(acc[1], q, extP1, extN1, 2 * half + 1, hbuf, rowAddr, psum);
  }
  __syncthreads();                               // h1 complete

  // ================= L1 =================
  kloop2<16>(hbufH, pL1, lane, q, c, b31, acc);
  bnd[T][half * 2 + q][c] = q ? acc[1][1][15] : acc[0][0][0];
  __syncthreads();
  {
    const float extP0 = bnd[T][half ? 1 : 3][c];
    const float extN1 = bnd[T][half ? 0 : 2][c];
    const float extN0 = xchg32(0.f, acc[1][0][0], q);
    const float extP1 = xchg32(acc[0][1][15], 0.f, q);
    epi_sub<1>(acc[0], q, extP0, extN0, 2 * half + 0, hbuf, rowAddr, psum);
    epi_sub<1>(acc[1], q, extP1, extN1, 2 * half + 1, hbuf, rowAddr, psum);
  }
  __syncthreads();                               // h2 complete

  // ================= L2 (pool only) =================
  kloop2<16>(hbufH, pL2, lane, q, c, b32, acc);
  bnd[T][half * 2 + q][c] = q ? acc[1][1][15] : acc[0][0][0];
  __syncthreads();
  {
    const float extP0 = bnd[T][half ? 1 : 3][c];
    const float extN1 = bnd[T][half ? 0 : 2][c];
    const float extN0 = xchg32(0.f, acc[1][0][0], q);
    const float extP1 = xchg32(acc[0][1][15], 0.f, q);
    epi_sub<2>(acc[0], q, extP0, extN0, 2 * half + 0, hbuf, rowAddr, psum);
    epi_sub<2>(acc[1], q, extP1, extN1, 2 * half + 1, hbuf, rowAddr, psum);
  }
  const float s2 = psum + xchg32(psum, psum, q); // q-pair sum (128 nodes of half)
  if (q == 0) pool[half][T][c] = s2;
  __syncthreads();
  if (tid < 256)
    out[b * 256 + tid] =
        (pool[0][tid >> 5][tid & 31] + pool[1][tid >> 5][tid & 31]) * (1.0f / 256.0f);
}

// ---------------- launch ----------------
extern "C" void kernel_launch(void* const* d_in, const int* in_sizes, int n_in,
                              void* d_out, int out_size, void* d_ws, size_t ws_size,
                              hipStream_t stream) {
  const float* x  = (const float*)d_in[0];
  const float* t  = (const float*)d_in[1];
  const float* tw = (const float*)d_in[2];
  const float* tb = (const float*)d_in[3];
  const float* W0 = (const float*)d_in[4];
  const float* b0 = (const float*)d_in[5];
  const float* W1 = (const float*)d_in[6];
  const float* b1 = (const float*)d_in[7];
  const float* W2 = (const float*)d_in[8];
  const float* b2 = (const float*)d_in[9];

  unsigned short* packW = (unsigned short*)d_ws;   // 167936 shorts
  float* out = (float*)d_out;

  pack_kernel<<<41, 512, 0, stream>>>(W0, W1, W2, packW);
  poly_kernel<<<1024, 1024, 0, stream>>>(x, t, tw, tb, packW, b0, b1, b2, out);
}

// Round 13
// 176.813 us; speedup vs baseline: 1.0619x; 1.0619x over previous
//
#include <hip/hip_runtime.h>
#include <cstdint>

typedef __attribute__((ext_vector_type(8)))  short bf16x8;   // 8 x bf16 (4 VGPR)
typedef __attribute__((ext_vector_type(16))) float f32x16;   // MFMA 32x32 acc
typedef __attribute__((ext_vector_type(4)))  int   i32x4;

__device__ __forceinline__ unsigned short f2bf(float x) {    // RNE fp32->bf16
  unsigned u = __float_as_uint(x);
  u += 0x7fffu + ((u >> 16) & 1u);
  return (unsigned short)(u >> 16);
}
// packed f32x2 -> bf16x2 in ONE instruction (no builtin on gfx950; inline asm)
__device__ __forceinline__ unsigned pk2bf(float lo, float hi) {
  unsigned r;
  asm("v_cvt_pk_bf16_f32 %0, %1, %2" : "=v"(r) : "v"(lo), "v"(hi));
  return r;
}
__device__ __forceinline__ float silu_f(float v) {
  return v * __builtin_amdgcn_rcpf(1.0f + __expf(-v));
}

// half-exchange without the LDS pipe: lanes 0-31 receive A from lane+32,
// lanes 32-63 receive B from lane-32  (== __shfl_xor(q ? A : B, 32)).
__device__ __forceinline__ float xchg32(float A, float B, int q) {
#if defined(__has_builtin)
#if __has_builtin(__builtin_amdgcn_permlane32_swap)
  auto r = __builtin_amdgcn_permlane32_swap(__float_as_uint(A), __float_as_uint(B),
                                            false, false);
  return __uint_as_float(q ? r[0] : r[1]);
#else
  return __shfl_xor(q ? A : B, 32);
#endif
#else
  return __shfl_xor(q ? A : B, 32);
#endif
}

// ---- pack W/3 into MFMA B-frag order via LDS transpose (coalesced R+W).
// dest layout: [layer][g(64 cols)][t(32-col tile)][kt][lane][8], K0 padded 134->144.
__global__ void pack_kernel(const float* __restrict__ W0, const float* __restrict__ W1,
                            const float* __restrict__ W2,
                            unsigned short* __restrict__ packW) {
  __shared__ float ldsF[16][257];
  const int s = blockIdx.x, tid = threadIdx.x;
  const float* W; int KT, kmax, base, kt;
  if (s < 9)       { W = W0; KT = 9;  kmax = 134; base = 0;      kt = s; }
  else if (s < 25) { W = W1; KT = 16; kmax = 256; base = 36864;  kt = s - 9; }
  else             { W = W2; KT = 16; kmax = 256; base = 102400; kt = s - 25; }
  const int k0 = kt * 16;
#pragma unroll
  for (int i = 0; i < 8; ++i) {                 // 512 thr x 8 = 16 x 256 floats
    const int idx = i * 512 + tid;
    const int kl = idx >> 8, col = idx & 255;
    const int kg = k0 + kl;
    ldsF[kl][col] = (kg < kmax) ? W[kg * 256 + col] * 0.33333334f : 0.0f;
  }
  __syncthreads();
  const int g = tid >> 7, t = (tid >> 6) & 1, lane = tid & 63;
  const int col = g * 64 + t * 32 + (lane & 31);
  const int kb = 8 * (lane >> 5);
  unsigned u0 = pk2bf(ldsF[kb + 0][col], ldsF[kb + 1][col]);
  unsigned u1 = pk2bf(ldsF[kb + 2][col], ldsF[kb + 3][col]);
  unsigned u2 = pk2bf(ldsF[kb + 4][col], ldsF[kb + 5][col]);
  unsigned u3 = pk2bf(ldsF[kb + 6][col], ldsF[kb + 7][col]);
  unsigned short* dst = packW + base + g * (KT * 1024) + t * (KT * 512) + kt * 512 + lane * 8;
  i32x4 v = { (int)u0, (int)u1, (int)u2, (int)u3 };
  *(i32x4*)dst = v;
}

// ======================================================================
// r13: r10 base (8 waves, resident Bf) with PAIR-wise fblocks:
//   fblockP1(L): kloop{subs 0,1}(L) [reads h rows 0..127, 4 indep MFMA chains]
//                ∥ epi{subs 2,3}(L-1) [writes h rows 128..255]
//   BAR
//   fblockP2(L): kloop{subs 2,3}(L) ∥ epi{subs 0,1}(L) [defers nodes 0,127]
//   fixes(L) [nodes 0,127 from live accA/accB]; Bf(L+1) preload; BAR
// 2 barriers/layer (6 total), 4 MFMA chains/kt (2x ILP vs r10), defers cut to 2.
// Node map: pair P covers nodes [128P,128P+128) as 4 tiles tt; within tile
// node = 128P + 32tt + 16q + r; C row = (r&3)+8*(r>>2)+4q (verified).
// s~[n] = (h W/3)[n] + bias/3; y[n] = silu(s~[n-1]+s~[n]+s~[n+1]).
// L0 temb-fold: tW once per wave (broadcast A); L0 K=16 (1 kt).
// h[256][256] bf16 in 128KB LDS, 16B-slot XOR swizzle. Bf 64 VGPR resident.
// Budget: accA+accB 128 (AGPR) + Bf 64 + ~50 arch ~= 242 <= 256.
// ======================================================================

__device__ __forceinline__ f32x16 MF(const bf16x8 a, const bf16x8 b, const f32x16 c) {
  return __builtin_amdgcn_mfma_f32_32x32x16_bf16(a, b, c, 0, 0, 0);
}

// one epilogue pair-of-values p (tile tt=p>>3, rows rp,rp+1) of a 4-tile pair
template <int ELAYER, bool DEFER>
__device__ __forceinline__ void epi_pairP(
    const int p, const f32x16* aO, const int q,
    const float* I, const float* X, const float extP, const float extN,
    const int epiPair, unsigned short* __restrict__ hbuf,
    const int* rowAddr, float& psum) {
  const int tt = p >> 3, rp = (p & 7) * 2;
  const float mid = aO[tt][rp] + aO[tt][rp + 1];
  float prev, next;
  if (rp > 0) prev = aO[tt][rp - 1];
  else        prev = q ? I[tt] : (tt == 0 ? extP : X[tt - 1]);
  if (rp < 14) next = aO[tt][rp + 2];
  else         next = q ? (tt == 3 ? extN : X[tt]) : I[tt];
  const float y0 = silu_f(prev + mid);
  const float y1 = silu_f(mid + next);
  const bool c0 = !(DEFER && tt == 0 && rp == 0 && q == 0);    // node 0
  const bool c1 = !(DEFER && tt == 3 && rp == 14 && q == 1);   // node 127
  if constexpr (ELAYER == 2) {
    if (c0) psum += y0;
    if (c1) psum += y1;
  } else {
    const unsigned u = pk2bf(y0, y1);
    char* bp = (char*)hbuf + (epiPair * 4 + tt) * 16384;
    if (c0) *(unsigned short*)(bp + rowAddr[rp])     = (unsigned short)u;
    if (c1) *(unsigned short*)(bp + rowAddr[rp + 1]) = (unsigned short)(u >> 16);
  }
}

// pair fblock: kloop over 4 tiles of readPair (4 indep MFMA chains), interleaved
// 2 epi-pairs/kt with the epilogue of epiPair (aO), branch-free unrolled.
template <int KT, int ELAYER, bool DOEPI, bool DEFER>
__device__ __forceinline__ void fblockP(
    unsigned short* __restrict__ hbuf, const int readPair, const int epiPair,
    const bf16x8* Bf, const int q, const int c, const float bias3,
    f32x16* aN, const f32x16* aO, const float extP, const float extN,
    const int* rowAddr, float& psum) {
  float I[4], X[3];
  if constexpr (DOEPI) {
#pragma unroll
    for (int tt = 0; tt < 4; ++tt) I[tt] = xchg32(aO[tt][0], aO[tt][15], q);
#pragma unroll
    for (int tt = 0; tt < 3; ++tt) X[tt] = xchg32(aO[tt][15], aO[tt + 1][0], q);
  }
#pragma unroll
  for (int tt = 0; tt < 4; ++tt)
#pragma unroll
    for (int j = 0; j < 16; ++j) aN[tt][j] = bias3;
  const unsigned short* rb = hbuf + readPair * 32768 + c * 256;
#pragma unroll
  for (int kt = 0; kt < KT; ++kt) {
    const unsigned short* ap = rb + (((2 * kt + q) ^ c) * 8);
    const bf16x8 a0 = *(const bf16x8*)(ap);
    const bf16x8 a1 = *(const bf16x8*)(ap + 8192);
    const bf16x8 a2 = *(const bf16x8*)(ap + 16384);
    const bf16x8 a3 = *(const bf16x8*)(ap + 24576);
    aN[0] = MF(a0, Bf[kt], aN[0]);
    aN[1] = MF(a1, Bf[kt], aN[1]);
    aN[2] = MF(a2, Bf[kt], aN[2]);
    aN[3] = MF(a3, Bf[kt], aN[3]);
    if constexpr (DOEPI) {
#pragma unroll
      for (int p = (kt * 32) / KT; p < ((kt + 1) * 32) / KT; ++p)
        epi_pairP<ELAYER, DEFER>(p, aO, q, I, X, extP, extN, epiPair,
                                 hbuf, rowAddr, psum);
    }
  }
}

template <int ELAYER>
__device__ __forceinline__ void epi_onlyP(
    const f32x16* aO, const int q, const float extP, const float extN,
    const int epiPair, unsigned short* __restrict__ hbuf,
    const int* rowAddr, float& psum) {
  float I[4], X[3];
#pragma unroll
  for (int tt = 0; tt < 4; ++tt) I[tt] = xchg32(aO[tt][0], aO[tt][15], q);
#pragma unroll
  for (int tt = 0; tt < 3; ++tt) X[tt] = xchg32(aO[tt][15], aO[tt + 1][0], q);
#pragma unroll
  for (int p = 0; p < 32; ++p)
    epi_pairP<ELAYER, false>(p, aO, q, I, X, extP, extN, epiPair,
                             hbuf, rowAddr, psum);
}

// deferred nodes 0 (q0) and 127 (q1) of pair{0,1}, from live accA/accB
template <int ELAYER>
__device__ __forceinline__ void fixesP(
    const f32x16* aA, const f32x16* aB, const int q,
    unsigned short* __restrict__ hbuf, const int* rowAddr, float& psum) {
  const float r128 = xchg32(0.f, aB[0][0], q);    // q1 <- s~[128]
  const float r255 = xchg32(aB[3][15], 0.f, q);   // q0 <- s~[255]
  if (q) {
    const float y = silu_f(aA[3][14] + aA[3][15] + r128);      // node 127
    if constexpr (ELAYER == 2) psum += y;
    else *(unsigned short*)((char*)hbuf + 3 * 16384 + rowAddr[15]) = f2bf(y);
  } else {
    const float y = silu_f(r255 + aA[0][0] + aA[0][1]);        // node 0
    if constexpr (ELAYER == 2) psum += y;
    else *(unsigned short*)((char*)hbuf + rowAddr[0]) = f2bf(y);
  }
}

// ---------------- main fused kernel: 1 block = 1 graph, 8 waves x 32 cols ----------
__global__ __launch_bounds__(512, 1) void poly_kernel(
    const float* __restrict__ x, const float* __restrict__ t,
    const float* __restrict__ tw, const float* __restrict__ tb,
    const unsigned short* __restrict__ packW,
    const float* __restrict__ B0, const float* __restrict__ B1,
    const float* __restrict__ B2, float* __restrict__ out) {
  __shared__ __align__(16) unsigned short hbuf[65536];  // 128 KiB, swizzled
  __shared__ __align__(16) unsigned short tmpl[160];    // h0 template (temb+pads)

  const int tid = threadIdx.x;
  const int w = tid >> 6, lane = tid & 63, q = lane >> 5, c = lane & 31;
  const int b = blockIdx.x;

  // ---- fused time MLP: temb = silu(sinemb(t[b]) @ tw + tb) ----
  {
    float* scr = (float*)hbuf;        // f32 scratch (overwritten later)
    if (tid < 128) {
      const float tv = t[b];
      const int i = tid & 63;
      const float f = expf(-0.14619588396823767f * (float)i);  // log(1e4)/63
      const float ang = tv * f;
      scr[tid] = (tid < 64) ? sinf(ang) : cosf(ang);
    }
    __syncthreads();
    {
      const int j = tid & 127, p = tid >> 7;   // 4-way k-split over the block
      float a = 0.f;
#pragma unroll 8
      for (int kk = 0; kk < 32; ++kk) a += scr[p * 32 + kk] * tw[(p * 32 + kk) * 128 + j];
      scr[128 + tid] = a;
    }
    __syncthreads();
    if (tid < 128) {
      const float a = tb[tid] + scr[128 + tid] + scr[256 + tid] + scr[384 + tid] + scr[512 + tid];
      tmpl[6 + tid] = f2bf(silu_f(a));
      if (tid < 6)  tmpl[tid] = 0;
      if (tid < 26) tmpl[134 + tid] = 0;   // pad k 134..159 = 0
    }
    __syncthreads();
  }

  // B slices: wave w <-> group g=w>>1, tile t=w&1 (cols 32w..32w+31)
  const unsigned short* pL0 = packW + (w >> 1) * (9 * 1024) + (w & 1) * (9 * 512);
  const unsigned short* pL1 = packW + 36864 + (w >> 1) * (16 * 1024) + (w & 1) * (16 * 512);
  const unsigned short* pL2 = packW + 102400 + (w >> 1) * (16 * 1024) + (w & 1) * (16 * 512);
  bf16x8 Bf[16];
#pragma unroll
  for (int kt = 0; kt < 9; ++kt) Bf[kt] = *(const bf16x8*)(pL0 + kt * 512 + lane * 8);
  const float b31 = B1[w * 32 + c] * 0.33333334f;
  const float b32 = B2[w * 32 + c] * 0.33333334f;

  // ---- tW fold: node-invariant L0 part (temb @ W0/3) once per wave ----
  float initL0;
  {
    f32x16 Ct;
#pragma unroll
    for (int j = 0; j < 16; ++j) Ct[j] = 0.f;
#pragma unroll
    for (int kt = 0; kt < 9; ++kt) {
      const bf16x8 at = *(const bf16x8*)(tmpl + kt * 16 + q * 8);
      Ct = MF(at, Bf[kt], Ct);
    }
    initL0 = Ct[0] + B0[w * 32 + c] * 0.33333334f;
  }

  // ---- build h0 (features only): slots 0,1 per node = [xy, pe, 0-pad] ----
  {
    const int node = tid >> 1, sl = tid & 1;
    i32x4 d = {0, 0, 0, 0};
    if (sl == 0) {
      const float2 xy = ((const float2*)x)[b * 256 + node];
      const float th = 0.024543692605870074f * (float)node;   // 2*pi/256
      d.x = (int)pk2bf(xy.x, xy.y);
      d.y = (int)pk2bf(sinf(th), cosf(th));
      d.z = (int)pk2bf(sinf(2.f * th), cosf(2.f * th));
    }
    const int m = (node & 3) + 8 * ((node >> 2) & 3) + 4 * ((node >> 4) & 1);
    const int R = (node & ~31) | m;            // permuted LDS row
    *(i32x4*)(hbuf + R * 256 + ((sl ^ m) * 8)) = d;
  }

  // per-lane h'-write byte addresses (row within tile; r compile-time)
  int rowAddr[16];
  const int slotW = 4 * w + (c >> 3), offW = (c & 7) * 2;    // k-index = 32w+c
#pragma unroll
  for (int r = 0; r < 16; ++r) {
    const int row = (r & 3) + 8 * (r >> 2) + 4 * q;
    rowAddr[r] = row * 512 + ((slotW ^ row) * 16) + offW;
  }
  __syncthreads();   // h0 ready

  f32x16 accA[4], accB[4];
  float psum = 0.f, extP, extN;

  // ================= L0 (K=16: coords+pe; temb folded into initL0) =================
  fblockP<1, 0, false, false>(hbuf, 0, 0, Bf, q, c, initL0, accA, accA, 0.f, 0.f, rowAddr, psum);
  __syncthreads();                               // pair-0 reads of h0 done
  fblockP<1, 0, true, true>(hbuf, 1, 0, Bf, q, c, initL0, accB, accA, 0.f, 0.f, rowAddr, psum);
#pragma unroll
  for (int kt = 0; kt < 16; ++kt) Bf[kt] = *(const bf16x8*)(pL1 + kt * 512 + lane * 8);
  fixesP<0>(accA, accB, q, hbuf, rowAddr, psum);
  __syncthreads();                               // h1 rows 0..127 + fixes done

  // ================= L1 =================
  extP = xchg32(accA[3][15], 0.f, q);            // s~(L0)[127] -> q0
  extN = xchg32(0.f, accA[0][0], q);             // s~(L0)[0]   -> q1
  fblockP<16, 0, true, false>(hbuf, 0, 1, Bf, q, c, b31, accA, accB, extP, extN, rowAddr, psum);
  __syncthreads();                               // h1 rows 128..255 written; pair-0 reads done
  fblockP<16, 1, true, true>(hbuf, 1, 0, Bf, q, c, b31, accB, accA, 0.f, 0.f, rowAddr, psum);
#pragma unroll
  for (int kt = 0; kt < 16; ++kt) Bf[kt] = *(const bf16x8*)(pL2 + kt * 512 + lane * 8);
  fixesP<1>(accA, accB, q, hbuf, rowAddr, psum);
  __syncthreads();

  // ================= L2 (epilogues pool into psum) =================
  extP = xchg32(accA[3][15], 0.f, q);            // s~(L1)[127]
  extN = xchg32(0.f, accA[0][0], q);             // s~(L1)[0]
  fblockP<16, 1, true, false>(hbuf, 0, 1, Bf, q, c, b32, accA, accB, extP, extN, rowAddr, psum);
  __syncthreads();                               // h2 rows 128..255 written; pair-0 reads done
  fblockP<16, 2, true, true>(hbuf, 1, 0, Bf, q, c, b32, accB, accA, 0.f, 0.f, rowAddr, psum);
  fixesP<2>(accA, accB, q, hbuf, rowAddr, psum);
  extP = xchg32(accA[3][15], 0.f, q);            // s~(L2)[127]
  extN = xchg32(0.f, accA[0][0], q);             // s~(L2)[0]
  epi_onlyP<2>(accB, q, extP, extN, 1, hbuf, rowAddr, psum);

  const float s2 = psum + xchg32(psum, psum, q);
  if (q == 0) out[b * 256 + w * 32 + c] = s2 * (1.0f / 256.0f);
}

// ---------------- launch ----------------
extern "C" void kernel_launch(void* const* d_in, const int* in_sizes, int n_in,
                              void* d_out, int out_size, void* d_ws, size_t ws_size,
                              hipStream_t stream) {
  const float* x  = (const float*)d_in[0];
  const float* t  = (const float*)d_in[1];
  const float* tw = (const float*)d_in[2];
  const float* tb = (const float*)d_in[3];
  const float* W0 = (const float*)d_in[4];
  const float* b0 = (const float*)d_in[5];
  const float* W1 = (const float*)d_in[6];
  const float* b1 = (const float*)d_in[7];
  const float* W2 = (const float*)d_in[8];
  const float* b2 = (const float*)d_in[9];

  unsigned short* packW = (unsigned short*)d_ws;   // 167936 shorts
  float* out = (float*)d_out;

  pack_kernel<<<41, 512, 0, stream>>>(W0, W1, W2, packW);
  poly_kernel<<<1024, 512, 0, stream>>>(x, t, tw, tb, packW, b0, b1, b2, out);
}

// Round 14
// 174.643 us; speedup vs baseline: 1.0751x; 1.0124x over previous
//
#include <hip/hip_runtime.h>
#include <cstdint>

typedef __attribute__((ext_vector_type(8)))  short bf16x8;   // 8 x bf16 (4 VGPR)
typedef __attribute__((ext_vector_type(16))) float f32x16;   // MFMA 32x32 acc
typedef __attribute__((ext_vector_type(4)))  int   i32x4;

__device__ __forceinline__ unsigned short f2bf(float x) {    // RNE fp32->bf16
  unsigned u = __float_as_uint(x);
  u += 0x7fffu + ((u >> 16) & 1u);
  return (unsigned short)(u >> 16);
}
// packed f32x2 -> bf16x2 in ONE instruction (no builtin on gfx950; inline asm)
__device__ __forceinline__ unsigned pk2bf(float lo, float hi) {
  unsigned r;
  asm("v_cvt_pk_bf16_f32 %0, %1, %2" : "=v"(r) : "v"(lo), "v"(hi));
  return r;
}
__device__ __forceinline__ float silu_f(float v) {
  return v * __builtin_amdgcn_rcpf(1.0f + __expf(-v));
}

// half-exchange without the LDS pipe: lanes 0-31 receive A from lane+32,
// lanes 32-63 receive B from lane-32  (== __shfl_xor(q ? A : B, 32)).
__device__ __forceinline__ float xchg32(float A, float B, int q) {
#if defined(__has_builtin)
#if __has_builtin(__builtin_amdgcn_permlane32_swap)
  auto r = __builtin_amdgcn_permlane32_swap(__float_as_uint(A), __float_as_uint(B),
                                            false, false);
  return __uint_as_float(q ? r[0] : r[1]);
#else
  return __shfl_xor(q ? A : B, 32);
#endif
#else
  return __shfl_xor(q ? A : B, 32);
#endif
}

// ---- pack W/3 into MFMA B-frag order via LDS transpose (coalesced R+W).
// 1/3 aggregation factor folded into the weights; bias folded into acc init.
// dest layout: [layer][g(64 cols)][t(32-col tile)][kt][lane][8], K0 padded 134->144.
__global__ void pack_kernel(const float* __restrict__ W0, const float* __restrict__ W1,
                            const float* __restrict__ W2,
                            unsigned short* __restrict__ packW) {
  __shared__ float ldsF[16][257];
  const int s = blockIdx.x, tid = threadIdx.x;
  const float* W; int KT, kmax, base, kt;
  if (s < 9)       { W = W0; KT = 9;  kmax = 134; base = 0;      kt = s; }
  else if (s < 25) { W = W1; KT = 16; kmax = 256; base = 36864;  kt = s - 9; }
  else             { W = W2; KT = 16; kmax = 256; base = 102400; kt = s - 25; }
  const int k0 = kt * 16;
#pragma unroll
  for (int i = 0; i < 8; ++i) {                 // 512 thr x 8 = 16 x 256 floats
    const int idx = i * 512 + tid;
    const int kl = idx >> 8, col = idx & 255;
    const int kg = k0 + kl;
    ldsF[kl][col] = (kg < kmax) ? W[kg * 256 + col] * 0.33333334f : 0.0f;
  }
  __syncthreads();
  const int g = tid >> 7, t = (tid >> 6) & 1, lane = tid & 63;
  const int col = g * 64 + t * 32 + (lane & 31);
  const int kb = 8 * (lane >> 5);
  unsigned u0 = pk2bf(ldsF[kb + 0][col], ldsF[kb + 1][col]);
  unsigned u1 = pk2bf(ldsF[kb + 2][col], ldsF[kb + 3][col]);
  unsigned u2 = pk2bf(ldsF[kb + 4][col], ldsF[kb + 5][col]);
  unsigned u3 = pk2bf(ldsF[kb + 6][col], ldsF[kb + 7][col]);
  unsigned short* dst = packW + base + g * (KT * 1024) + t * (KT * 512) + kt * 512 + lane * 8;
  i32x4 v = { (int)u0, (int)u1, (int)u2, (int)u3 };
  *(i32x4*)dst = v;
}

// ======================================================================
// r14 = r10 (best verified: bench 174.3, poly ~118) + T5 s_setprio around the
// per-kt MFMA pair. fblock waves drift out of phase after barriers (epi lengths
// differ) -> scheduler can prefer the MFMA-entering wave. Zero reg/numerics cost.
// Wave w owns ALL 256 nodes x cols [32w,32w+32); node = 32nt+16q+r in-lane.
// s~[n] = (h W/3)[n] + bias/3; y[n] = silu(s~[n-1]+s~[n]+s~[n+1]).
// L0 temb-fold; 4 subs of 2 tiles, ping-pong acc, kloop interleaved 1:1 with
// prev-sub epilogue, depth-1 prefetch; permlane32 boundary exchange;
// cvt_pk_bf16 stores; 128KB swizzled h; resident Bf (64 VGPR).
// ======================================================================

// one epilogue PAIR p (values r=2(p&7), +1 of tile t=p>>3); mid-sum shared
template <int ELAYER, bool DF, bool DL>
__device__ __forceinline__ void epi_pair(
    const int p, const f32x16* accEpi, const int q,
    const float recvI0, const float recvI1, const float recvX,
    const float extP, const float extN,
    const int epiSub, unsigned short* __restrict__ hbuf,
    const int* rowAddr, float& psum) {
  const int t = p >> 3, rp = (p & 7) * 2;
  const float mid = accEpi[t][rp] + accEpi[t][rp + 1];
  float prev, next;
  if (rp > 0) prev = accEpi[t][rp - 1];
  else        prev = q ? (t ? recvI1 : recvI0) : (t ? recvX : extP);
  if (rp < 14) next = accEpi[t][rp + 2];
  else         next = q ? (t ? extN : recvX) : (t ? recvI1 : recvI0);
  const float y0 = silu_f(prev + mid);
  const float y1 = silu_f(mid + next);
  const bool c0 = !(DF && t == 0 && rp == 0 && q == 0);
  const bool c1 = !(DL && t == 1 && rp == 14 && q == 1);
  if constexpr (ELAYER == 2) {
    if (c0) psum += y0;
    if (c1) psum += y1;
  } else {
    const unsigned u = pk2bf(y0, y1);
    char* bp = (char*)hbuf + (2 * epiSub + t) * 16384;
    if (c0) *(unsigned short*)(bp + rowAddr[rp])     = (unsigned short)u;
    if (c1) *(unsigned short*)(bp + rowAddr[rp + 1]) = (unsigned short)(u >> 16);
  }
}

// fused block: kloop over 2 tiles of readSub (acc init = bias-ish scalar),
// depth-1 A prefetch, interleaved with epilogue pairs of epiSub (prev sub).
// setprio(1) wraps the MFMA issue pair (T5).
template <int KT, int ELAYER, bool DOEPI, bool DF, bool DL>
__device__ __forceinline__ void fblock(
    unsigned short* __restrict__ hbuf, const int readSub, const int epiSub,
    const bf16x8* Bf, const int q, const int c, const float bias3,
    f32x16* accOut, const f32x16* accEpi,
    const float extP, const float extN,
    const int* rowAddr, float& psum) {
  float recvI0 = 0.f, recvI1 = 0.f, recvX = 0.f;
  if constexpr (DOEPI) {
    recvI0 = xchg32(accEpi[0][0],  accEpi[0][15], q);
    recvI1 = xchg32(accEpi[1][0],  accEpi[1][15], q);
    recvX  = xchg32(accEpi[0][15], accEpi[1][0],  q);
  }
#pragma unroll
  for (int t2 = 0; t2 < 2; ++t2)
#pragma unroll
    for (int j = 0; j < 16; ++j) accOut[t2][j] = bias3;
  const unsigned short* rb = hbuf + readSub * 16384 + c * 256;
  bf16x8 a0 = *(const bf16x8*)(rb + ((q ^ c) * 8));
  bf16x8 a1 = *(const bf16x8*)(rb + ((q ^ c) * 8) + 8192);
#pragma unroll
  for (int kt = 0; kt < KT; ++kt) {
    const bf16x8 u0 = a0, u1 = a1;
    if (kt + 1 < KT) {                          // depth-1 prefetch
      const unsigned short* nb = rb + (((2 * (kt + 1) + q) ^ c) * 8);
      a0 = *(const bf16x8*)(nb);
      a1 = *(const bf16x8*)(nb + 8192);
    }
    __builtin_amdgcn_s_setprio(1);              // T5: favor MFMA-entering wave
    accOut[0] = __builtin_amdgcn_mfma_f32_32x32x16_bf16(u0, Bf[kt], accOut[0], 0, 0, 0);
    accOut[1] = __builtin_amdgcn_mfma_f32_32x32x16_bf16(u1, Bf[kt], accOut[1], 0, 0, 0);
    __builtin_amdgcn_s_setprio(0);
    if constexpr (DOEPI) {
#pragma unroll
      for (int p = (kt * 16) / KT; p < ((kt + 1) * 16) / KT; ++p)
        epi_pair<ELAYER, DF, DL>(p, accEpi, q, recvI0, recvI1, recvX, extP, extN,
                                 epiSub, hbuf, rowAddr, psum);
    }
  }
}

template <int ELAYER>
__device__ __forceinline__ void epi_only(
    const f32x16* accEpi, const int q, const float extP, const float extN,
    const int epiSub, unsigned short* __restrict__ hbuf,
    const int* rowAddr, float& psum) {
  const float recvI0 = xchg32(accEpi[0][0],  accEpi[0][15], q);
  const float recvI1 = xchg32(accEpi[1][0],  accEpi[1][15], q);
  const float recvX  = xchg32(accEpi[0][15], accEpi[1][0],  q);
#pragma unroll
  for (int p = 0; p < 16; ++p)
    epi_pair<ELAYER, false, false>(p, accEpi, q, recvI0, recvI1, recvX, extP, extN,
                                   epiSub, hbuf, rowAddr, psum);
}

// node 64e+63 (q1 lanes): prev/cur in accEpi[1][14..15], next = new sub's node 64e+64
template <int ELAYER>
__device__ __forceinline__ void defer_last(
    const f32x16* accEpi, const float accNew00, const int epiSub,
    const int q, unsigned short* __restrict__ hbuf,
    const int* rowAddr, float& psum) {
  const float recv = xchg32(0.f, accNew00, q);   // q1 <- s~[64e+64]
  const float y = silu_f(accEpi[1][14] + accEpi[1][15] + recv);
  if (q) {
    if constexpr (ELAYER == 2) psum += y;
    else *(unsigned short*)((char*)hbuf + (2 * epiSub + 1) * 16384 + rowAddr[15]) = f2bf(y);
  }
}

// node 0 (q0 lanes): prev = s~[255], cur/next = saved s~[0], s~[1]
template <int ELAYER>
__device__ __forceinline__ void fix_node0(
    const float s255src, const float sv0, const float sv1,
    const int q, unsigned short* __restrict__ hbuf,
    const int* rowAddr, float& psum) {
  const float recv = xchg32(s255src, 0.f, q);    // q0 <- s~[255]
  const float y = silu_f(recv + sv0 + sv1);
  if (!q) {
    if constexpr (ELAYER == 2) psum += y;
    else *(unsigned short*)((char*)hbuf + rowAddr[0]) = f2bf(y);
  }
}

// ---------------- main fused kernel: 1 block = 1 graph, 8 waves x 32 cols ----------
__global__ __launch_bounds__(512, 1) void poly_kernel(
    const float* __restrict__ x, const float* __restrict__ t,
    const float* __restrict__ tw, const float* __restrict__ tb,
    const unsigned short* __restrict__ packW,
    const float* __restrict__ B0, const float* __restrict__ B1,
    const float* __restrict__ B2, float* __restrict__ out) {
  __shared__ __align__(16) unsigned short hbuf[65536];  // 128 KiB: h[row][256] bf16, swizzled
  __shared__ __align__(16) unsigned short tmpl[160];    // h0 template (temb+pads)

  const int tid = threadIdx.x;
  const int w = tid >> 6, lane = tid & 63, q = lane >> 5, c = lane & 31;
  const int b = blockIdx.x;

  // ---- fused time MLP: temb = silu(sinemb(t[b]) @ tw + tb) ----
  {
    float* scr = (float*)hbuf;        // f32 scratch (overwritten later)
    if (tid < 128) {
      const float tv = t[b];
      const int i = tid & 63;
      const float f = expf(-0.14619588396823767f * (float)i);  // log(1e4)/63
      const float ang = tv * f;
      scr[tid] = (tid < 64) ? sinf(ang) : cosf(ang);
    }
    __syncthreads();
    {
      const int j = tid & 127, p = tid >> 7;   // 4-way k-split over the block
      float a = 0.f;
#pragma unroll 8
      for (int kk = 0; kk < 32; ++kk) a += scr[p * 32 + kk] * tw[(p * 32 + kk) * 128 + j];
      scr[128 + tid] = a;
    }
    __syncthreads();
    if (tid < 128) {
      const float a = tb[tid] + scr[128 + tid] + scr[256 + tid] + scr[384 + tid] + scr[512 + tid];
      tmpl[6 + tid] = f2bf(silu_f(a));
      if (tid < 6)  tmpl[tid] = 0;
      if (tid < 26) tmpl[134 + tid] = 0;   // pad k 134..159 = 0
    }
    __syncthreads();
  }

  // B slices: wave w <-> group g=w>>1, tile t=w&1 (cols 32w..32w+31)
  const unsigned short* pL0 = packW + (w >> 1) * (9 * 1024) + (w & 1) * (9 * 512);
  const unsigned short* pL1 = packW + 36864 + (w >> 1) * (16 * 1024) + (w & 1) * (16 * 512);
  const unsigned short* pL2 = packW + 102400 + (w >> 1) * (16 * 1024) + (w & 1) * (16 * 512);
  bf16x8 Bf[16];
#pragma unroll
  for (int kt = 0; kt < 9; ++kt) Bf[kt] = *(const bf16x8*)(pL0 + kt * 512 + lane * 8);
  const float b30 = B0[w * 32 + c] * 0.33333334f;
  const float b31 = B1[w * 32 + c] * 0.33333334f;
  const float b32 = B2[w * 32 + c] * 0.33333334f;

  // ---- tW fold: node-invariant part of L0 (temb @ W0/3), once per wave ----
  float initL0;
  {
    f32x16 Ct;
#pragma unroll
    for (int j = 0; j < 16; ++j) Ct[j] = 0.f;
#pragma unroll
    for (int kt = 0; kt < 9; ++kt) {
      const bf16x8 at = *(const bf16x8*)(tmpl + kt * 16 + q * 8);
      Ct = __builtin_amdgcn_mfma_f32_32x32x16_bf16(at, Bf[kt], Ct, 0, 0, 0);
    }
    initL0 = Ct[0] + b30;
  }

  // ---- build h0 (features only): slots 0,1 per node = [xy, pe, 0-pad] ----
  {
    const int node = tid >> 1, sl = tid & 1;
    i32x4 d = {0, 0, 0, 0};
    if (sl == 0) {
      const float2 xy = ((const float2*)x)[b * 256 + node];
      const float th = 0.024543692605870074f * (float)node;   // 2*pi/256
      d.x = (int)pk2bf(xy.x, xy.y);
      d.y = (int)pk2bf(sinf(th), cosf(th));
      d.z = (int)pk2bf(sinf(2.f * th), cosf(2.f * th));
    }
    const int m = (node & 3) + 8 * ((node >> 2) & 3) + 4 * ((node >> 4) & 1);
    const int R = (node & ~31) | m;            // permuted LDS row
    *(i32x4*)(hbuf + R * 256 + ((sl ^ m) * 8)) = d;
  }

  // per-lane h'-write byte addresses (row within tile; r compile-time)
  int rowAddr[16];
  const int slotW = 4 * w + (c >> 3), offW = (c & 7) * 2;    // k-index = 32w+c
#pragma unroll
  for (int r = 0; r < 16; ++r) {
    const int row = (r & 3) + 8 * (r >> 2) + 4 * q;
    rowAddr[r] = row * 512 + ((slotW ^ row) * 16) + offW;
  }
  __syncthreads();   // h0 ready

  f32x16 accA[2], accB[2];
  float psum = 0.f, sv0, sv1, extP, extN;

  // ================= L0 (K=16: coords+pe; temb folded into initL0) =================
  fblock<1, 0, false, false, false>(hbuf, 0, 0, Bf, q, c, initL0, accA, accA, 0.f, 0.f, rowAddr, psum);
  sv0 = accA[0][0]; sv1 = accA[0][1];                       // s~[0], s~[1] (q0)
  __syncthreads();
  fblock<1, 0, true, true, true>(hbuf, 1, 0, Bf, q, c, initL0, accB, accA, 0.f, 0.f, rowAddr, psum);
  defer_last<0>(accA, accB[0][0], 0, q, hbuf, rowAddr, psum);       // node 63
  extP = xchg32(accA[1][15], 0.f, q);                               // s~[63] -> q0
  __syncthreads();
  fblock<1, 0, true, false, true>(hbuf, 2, 1, Bf, q, c, initL0, accA, accB, extP, 0.f, rowAddr, psum);
  defer_last<0>(accB, accA[0][0], 1, q, hbuf, rowAddr, psum);       // node 127
  extP = xchg32(accB[1][15], 0.f, q);                               // s~[127]
  __syncthreads();
  fblock<1, 0, true, false, true>(hbuf, 3, 2, Bf, q, c, initL0, accB, accA, extP, 0.f, rowAddr, psum);
  // issue next-layer Bf loads FIRST (VMEM latency hides under fixup VALU + barrier)
#pragma unroll
  for (int kt = 0; kt < 16; ++kt) Bf[kt] = *(const bf16x8*)(pL1 + kt * 512 + lane * 8);
  defer_last<0>(accA, accB[0][0], 2, q, hbuf, rowAddr, psum);       // node 191
  fix_node0<0>(accB[1][15], sv0, sv1, q, hbuf, rowAddr, psum);      // node 0
  extP = xchg32(accA[1][15], 0.f, q);                               // s~[191]
  extN = xchg32(0.f, sv0, q);                                       // s~[0] -> q1
  __syncthreads();

  // ================= L1 =================
  fblock<16, 0, true, false, false>(hbuf, 0, 3, Bf, q, c, b31, accA, accB, extP, extN, rowAddr, psum);
  sv0 = accA[0][0]; sv1 = accA[0][1];
  __syncthreads();
  fblock<16, 1, true, true, true>(hbuf, 1, 0, Bf, q, c, b31, accB, accA, 0.f, 0.f, rowAddr, psum);
  defer_last<1>(accA, accB[0][0], 0, q, hbuf, rowAddr, psum);
  extP = xchg32(accA[1][15], 0.f, q);
  __syncthreads();
  fblock<16, 1, true, false, true>(hbuf, 2, 1, Bf, q, c, b31, accA, accB, extP, 0.f, rowAddr, psum);
  defer_last<1>(accB, accA[0][0], 1, q, hbuf, rowAddr, psum);
  extP = xchg32(accB[1][15], 0.f, q);
  __syncthreads();
  fblock<16, 1, true, false, true>(hbuf, 3, 2, Bf, q, c, b31, accB, accA, extP, 0.f, rowAddr, psum);
#pragma unroll
  for (int kt = 0; kt < 16; ++kt) Bf[kt] = *(const bf16x8*)(pL2 + kt * 512 + lane * 8);
  defer_last<1>(accA, accB[0][0], 2, q, hbuf, rowAddr, psum);
  fix_node0<1>(accB[1][15], sv0, sv1, q, hbuf, rowAddr, psum);
  extP = xchg32(accA[1][15], 0.f, q);
  extN = xchg32(0.f, sv0, q);
  __syncthreads();

  // ================= L2 (pool only; no LDS writes -> fewer barriers) =================
  fblock<16, 1, true, false, false>(hbuf, 0, 3, Bf, q, c, b32, accA, accB, extP, extN, rowAddr, psum);
  sv0 = accA[0][0]; sv1 = accA[0][1];
  __syncthreads();                              // epi(s3,L1) wrote rows 192..255
  fblock<16, 2, true, true, true>(hbuf, 1, 0, Bf, q, c, b32, accB, accA, 0.f, 0.f, rowAddr, psum);
  defer_last<2>(accA, accB[0][0], 0, q, hbuf, rowAddr, psum);
  extP = xchg32(accA[1][15], 0.f, q);
  fblock<16, 2, true, false, true>(hbuf, 2, 1, Bf, q, c, b32, accA, accB, extP, 0.f, rowAddr, psum);
  defer_last<2>(accB, accA[0][0], 1, q, hbuf, rowAddr, psum);
  extP = xchg32(accB[1][15], 0.f, q);
  fblock<16, 2, true, false, true>(hbuf, 3, 2, Bf, q, c, b32, accB, accA, extP, 0.f, rowAddr, psum);
  defer_last<2>(accA, accB[0][0], 2, q, hbuf, rowAddr, psum);
  fix_node0<2>(accB[1][15], sv0, sv1, q, hbuf, rowAddr, psum);
  extP = xchg32(accA[1][15], 0.f, q);
  extN = xchg32(0.f, sv0, q);
  epi_only<2>(accB, q, extP, extN, 3, hbuf, rowAddr, psum);

  const float s2 = psum + xchg32(psum, psum, q);
  if (q == 0) out[b * 256 + w * 32 + c] = s2 * (1.0f / 256.0f);
}

// ---------------- launch ----------------
extern "C" void kernel_launch(void* const* d_in, const int* in_sizes, int n_in,
                              void* d_out, int out_size, void* d_ws, size_t ws_size,
                              hipStream_t stream) {
  const float* x  = (const float*)d_in[0];
  const float* t  = (const float*)d_in[1];
  const float* tw = (const float*)d_in[2];
  const float* tb = (const float*)d_in[3];
  const float* W0 = (const float*)d_in[4];
  const float* b0 = (const float*)d_in[5];
  const float* W1 = (const float*)d_in[6];
  const float* b1 = (const float*)d_in[7];
  const float* W2 = (const float*)d_in[8];
  const float* b2 = (const float*)d_in[9];

  unsigned short* packW = (unsigned short*)d_ws;   // 167936 shorts
  float* out = (float*)d_out;

  pack_kernel<<<41, 512, 0, stream>>>(W0, W1, W2, packW);
  poly_kernel<<<1024, 512, 0, stream>>>(x, t, tw, tb, packW, b0, b1, b2, out);
}